// Round 5
// baseline (127.427 us; speedup 1.0000x reference)
//
#include <hip/hip_runtime.h>
#include <math.h>

#define G      7
#define NBOX   98
#define CH     30
#define RAWF   1470
#define BATCH  8192

// Wave-internal LDS visibility: drain this wave's outstanding DS ops.
#define WAVE_SYNC() asm volatile("s_waitcnt lgkmcnt(0)" ::: "memory")

__device__ __forceinline__ float sigmoidf_(float x) {
    return 1.0f / (1.0f + expf(-x));
}
// Broadcast lane i's value to all lanes (i wave-uniform). Pure VALU, no LDS.
__device__ __forceinline__ float rdlanef(float x, int i) {
    return __int_as_float(__builtin_amdgcn_readlane(__float_as_int(x), i));
}
// Correctly-rounded x/7 (Markstein 2-fma refinement == IEEE x/7.0f for normal x/q).
__device__ __forceinline__ float div7(float x) {
    const float r7 = 1.0f / 7.0f;          // RN(1/7), compile-time
    float q0 = x * r7;
    float e  = fmaf(-7.0f, q0, x);
    return fmaf(e, r7, q0);
}

__global__ __launch_bounds__(128, 8) void yolo_nms_kernel(
    const float* __restrict__ p,
    float* __restrict__ out_boxes,   // [B,98,4]
    float* __restrict__ out_scores,  // [B,98]
    float* __restrict__ out_labels,  // [B,98]
    float* __restrict__ out_keep)    // [B,98]
{
#pragma clang fp contract(off)
    // Only LDS use: per-wave sorted-box shuffle (push to rank slot, pull slot=lane).
    __shared__ __align__(16) float4 sboxS[2][NBOX];   // 3136 B
    __shared__ __align__(8)  float2 smetaS[2][NBOX];  // 1568 B (area, label)

    const int lane = threadIdx.x & 63;
    const int wv   = threadIdx.x >> 6;
    const int b    = blockIdx.x * 2 + wv;

    float4* sbox  = sboxS[wv];
    float2* smeta = smetaS[wv];

    const float* base = p + (size_t)b * RAWF;

    // ---- per-cell class argmax (once per cell, lanes 0..48) ----
    int labi = 0;
    if (lane < 49) {
        const float2* q2 = (const float2*)(base + lane * CH + 10);  // 8B aligned
        float2 c0 = q2[0];
        float best = c0.x; int bi = 0;
        if (c0.y > best) { best = c0.y; bi = 1; }
        #pragma unroll
        for (int k2 = 1; k2 < 10; ++k2) {
            float2 cv = q2[k2];
            if (cv.x > best) { best = cv.x; bi = 2 * k2; }
            if (cv.y > best) { best = cv.y; bi = 2 * k2 + 1; }
        }
        labi = bi + 1;
    }
    // label of box t lives at cell t>>1; pull cross-lane (no LDS alloc).
    float lblf[2];
    lblf[0] = (float)__builtin_amdgcn_ds_bpermute((lane >> 1) * 4, labi);
    lblf[1] = (float)__builtin_amdgcn_ds_bpermute((32 + (lane >> 1)) * 4, labi);

    // ---- decode 2 slots per lane (t = lane, lane+64) ----
    float4 bb[2]; float s[2], area[2]; bool vld[2];
    #pragma unroll
    for (int u = 0; u < 2; ++u) {
        const int t = lane + 64 * u;
        s[u] = -1.0f; vld[u] = false; area[u] = 0.0f;
        bb[u] = make_float4(0.f, 0.f, 0.f, 0.f);
        if (t < NBOX) {
            const int cell = t >> 1, j = t & 1;
            const int r = cell / G, c = cell - r * G;
            const float* q = base + cell * CH + j * 4;
            float2 xy = *(const float2*)q;        // tx, ty (8B aligned)
            float2 wh = *(const float2*)(q + 2);  // tw, th
            float conf = base[cell * CH + 8 + j];
            float gx = div7(sigmoidf_(xy.x) + (float)c);
            float gy = div7(sigmoidf_(xy.y) + (float)r);
            float hx = wh.x * 0.5f, hy = wh.y * 0.5f;
            bb[u] = make_float4(gx - hx, gy - hy, gx + hx, gy + hy);
            area[u] = fmaxf(bb[u].z - bb[u].x, 0.0f) * fmaxf(bb[u].w - bb[u].y, 0.0f);
            s[u] = sigmoidf_(conf);
            vld[u] = (s[u] > 0.5f);
            ((float4*)(out_boxes + (size_t)b * (NBOX * 4)))[t] = bb[u];
            out_scores[(size_t)b * NBOX + t] = s[u];
            out_labels[(size_t)b * NBOX + t] = lblf[u];
        }
    }

    // ---- V = number of valid boxes (valid = prefix of sorted order) ----
    const int V = __popcll(__ballot(vld[0])) + __popcll(__ballot(vld[1]));

    // ---- stable descending rank over original slots (masked scores, no LDS) ----
    // Candidate original indices: loop1 = 0..63 (slot0), loop2 = 64..97 (slot1).
    // All loop1 indices precede lane+64 -> rk1 tie-break is just '>='.
    // All loop2 indices exceed lane     -> rk0 tie-break term vanishes.
    const float ms0 = vld[0] ? s[0] : -1.0f;
    const float ms1 = vld[1] ? s[1] : -1.0f;
    int rk0 = 0, rk1 = 0;
    #pragma unroll 8
    for (int jj = 0; jj < 64; ++jj) {
        float a = rdlanef(ms0, jj);
        rk0 += (a > ms0) || ((a == ms0) && (jj < lane));
        rk1 += (a >= ms1);
    }
    #pragma unroll 8
    for (int jj = 0; jj < 34; ++jj) {
        float a = rdlanef(ms1, jj);
        rk0 += (a > ms0);
        rk1 += (a > ms1) || ((a == ms1) && (jj < lane));
    }

    // ---- push boxes to sorted slots; pull slot 'lane' into registers ----
    if (vld[0]) { sbox[rk0] = bb[0]; smeta[rk0] = make_float2(area[0], lblf[0]); }
    if (vld[1]) { sbox[rk1] = bb[1]; smeta[rk1] = make_float2(area[1], lblf[1]); }
    WAVE_SYNC();
    const float4 mb = sbox[lane];
    const float2 mm = smeta[lane];
    const float mlab = (lane < V) ? mm.y : -1.0f;   // sentinel kills garbage hits

    // ---- fused readlane-ballot NMS (mask build + greedy scan in one loop) ----
    unsigned long long k0 = 0ull, k1 = 0ull;
    // exact division-free predicate: RN(inter/uc) > 0.3f <=> inter > (0.3f+2^-26)*uc (exact in f64)
    const double UD = (double)0.3f + 0x1p-26;

#define ROW_HIT(I, HIT) do {                                             \
        float bx = rdlanef(mb.x, (I)), by = rdlanef(mb.y, (I));          \
        float bz = rdlanef(mb.z, (I)), bw = rdlanef(mb.w, (I));          \
        float ba = rdlanef(mm.x, (I)), bl = rdlanef(mlab, (I));          \
        float w = fmaxf(fminf(bz, mb.z) - fmaxf(bx, mb.x), 0.0f);        \
        float h = fmaxf(fminf(bw, mb.w) - fmaxf(by, mb.y), 0.0f);        \
        float inter = w * h;                                             \
        float uc = fmaxf(ba + mm.x - inter, 1e-9f);                      \
        HIT = ((double)inter > UD * (double)uc) && (bl == mlab);         \
    } while (0)

    if (V <= 64) {
        int i = 0;
        for (; i + 2 <= V; i += 2) {          // x2 unroll: independent rows, ILP
            bool h0, h1;
            ROW_HIT(i, h0);
            ROW_HIT(i + 1, h1);
            unsigned long long r0 = __ballot(h0);
            unsigned long long r1 = __ballot(h1);
            if ((r0 & k0) == 0ull) k0 |= 1ull << i;
            if ((r1 & k0) == 0ull) k0 |= 1ull << (i + 1);
        }
        if (i < V) {
            bool h0; ROW_HIT(i, h0);
            unsigned long long r0 = __ballot(h0);
            if ((r0 & k0) == 0ull) k0 |= 1ull << i;
        }
    } else {
        // rare (~0.1% of batches): V in (64, 98]
        const int i2c = (lane + 64 < NBOX) ? lane + 64 : NBOX - 1;
        const float4 mb2 = sbox[i2c];
        const float2 mm2 = smeta[i2c];
        const float mlab2 = (lane + 64 < V) ? mm2.y : -1.0f;
        for (int i = 0; i < V; ++i) {
            float bx, by, bz, bw, ba, bl;
            if (i < 64) {
                bx = rdlanef(mb.x, i);  by = rdlanef(mb.y, i);
                bz = rdlanef(mb.z, i);  bw = rdlanef(mb.w, i);
                ba = rdlanef(mm.x, i);  bl = rdlanef(mlab, i);
            } else {
                bx = rdlanef(mb2.x, i - 64);  by = rdlanef(mb2.y, i - 64);
                bz = rdlanef(mb2.z, i - 64);  bw = rdlanef(mb2.w, i - 64);
                ba = rdlanef(mm2.x, i - 64);  bl = rdlanef(mlab2, i - 64);
            }
            float w1 = fmaxf(fminf(bz, mb.z) - fmaxf(bx, mb.x), 0.0f);
            float h1 = fmaxf(fminf(bw, mb.w) - fmaxf(by, mb.y), 0.0f);
            float i1 = w1 * h1;
            float u1 = fmaxf(ba + mm.x - i1, 1e-9f);
            bool hit1 = ((double)i1 > UD * (double)u1) && (bl == mlab);
            float w2 = fmaxf(fminf(bz, mb2.z) - fmaxf(bx, mb2.x), 0.0f);
            float h2 = fmaxf(fminf(bw, mb2.w) - fmaxf(by, mb2.y), 0.0f);
            float i2 = w2 * h2;
            float u2 = fmaxf(ba + mm2.x - i2, 1e-9f);
            bool hit2 = ((double)i2 > UD * (double)u2) && (bl == mlab2);
            unsigned long long row0 = __ballot(hit1);
            unsigned long long row1 = __ballot(hit2);
            if (((row0 & k0) | (row1 & k1)) == 0ull) {
                if (i < 64) k0 |= 1ull << i;
                else        k1 |= 1ull << (i - 64);
            }
        }
    }
#undef ROW_HIT

    // ---- keep: lane knows its own ranks; no scatter needed ----
    float kv0 = 0.0f, kv1 = 0.0f;
    if (vld[0]) kv0 = (float)((((rk0 < 64) ? k0 : k1) >> (rk0 & 63)) & 1ull);
    if (vld[1]) kv1 = (float)((((rk1 < 64) ? k0 : k1) >> (rk1 & 63)) & 1ull);
    out_keep[(size_t)b * NBOX + lane] = kv0;
    if (lane + 64 < NBOX) out_keep[(size_t)b * NBOX + lane + 64] = kv1;
}

extern "C" void kernel_launch(void* const* d_in, const int* in_sizes, int n_in,
                              void* d_out, int out_size, void* d_ws, size_t ws_size,
                              hipStream_t stream) {
    const float* p = (const float*)d_in[0];
    float* out = (float*)d_out;
    float* out_boxes  = out;
    float* out_scores = out + (size_t)BATCH * NBOX * 4;
    float* out_labels = out_scores + (size_t)BATCH * NBOX;
    float* out_keep   = out_labels + (size_t)BATCH * NBOX;

    yolo_nms_kernel<<<BATCH / 2, 128, 0, stream>>>(p, out_boxes, out_scores,
                                                   out_labels, out_keep);
}